// Round 1
// baseline (225.103 us; speedup 1.0000x reference)
//
#include <hip/hip_runtime.h>
#include <hip/hip_bf16.h>

typedef __bf16 bf16;
typedef __bf16 bf16x4 __attribute__((ext_vector_type(4)));
typedef __bf16 bf16x8 __attribute__((ext_vector_type(8)));
typedef float  f32x4  __attribute__((ext_vector_type(4)));

#define DEVI static __device__ __forceinline__

constexpr int NB = 4;
constexpr int N1 = 4096;
constexpr int N2 = 2048;
constexpr int D  = 256;   // DIM1 = DIM2 = DK

DEVI f32x4 mfma16(bf16x8 a, bf16x8 b, f32x4 c) {
  return __builtin_amdgcn_mfma_f32_16x16x32_bf16(a, b, c, 0, 0, 0);
}

typedef const __attribute__((address_space(1))) void* gas_t;
typedef __attribute__((address_space(3))) void* las_t;

DEVI void gload_lds16(const void* g, void* l) {
  __builtin_amdgcn_global_load_lds((gas_t)g, (las_t)l, 16, 0, 0);
}

// ---------------------------------------------------------------------------
// Projection GEMM (NT): C[M,N] = A[M,256] * B[N,256]^T (+bias), bf16 MFMA.
// MODE 0 (Q): A=x2 M=8192, B=WQ N=256. out: Q fp32, Qb bf16, tanh(Q) bf16.
// MODE 1 (K): A=x1 M=16384, B=WK.     out: Kb bf16, tanh(K) bf16.
// MODE 2 (V^T): A=WV M=256, B=x1 N=16384, bias per-row. out: Vt bf16 [b][dk][m].
// Tile: BM=128, BN=64, BK=64; 256 threads (4 waves, 2x2), wave tile 64x32.
// ---------------------------------------------------------------------------
template<int MODE>
__global__ __launch_bounds__(256)
void proj_kernel(const float* __restrict__ A, const float* __restrict__ Bm,
                 const float* __restrict__ bias,
                 float* __restrict__ outF, bf16* __restrict__ out1,
                 bf16* __restrict__ out2)
{
  __shared__ bf16 As[128][64];
  __shared__ bf16 Bs[64][64];
  const int tid  = threadIdx.x;
  const int lane = tid & 63, wid = tid >> 6;
  const int wr = wid >> 1, wc = wid & 1;
  const int m0 = blockIdx.x * 128, n0 = blockIdx.y * 64;

  f32x4 acc[4][2];
#pragma unroll
  for (int i = 0; i < 4; ++i)
#pragma unroll
    for (int j = 0; j < 2; ++j) acc[i][j] = f32x4{0.f, 0.f, 0.f, 0.f};

  for (int kt = 0; kt < 4; ++kt) {
    const int k0 = kt * 64;
    if (kt) __syncthreads();
    // stage A tile [128][64] fp32 -> bf16 LDS
#pragma unroll
    for (int i = 0; i < 8; ++i) {
      int idx = i * 256 + tid;
      int r = idx >> 4, c4 = idx & 15;
      const float4 v = *(const float4*)(A + (size_t)(m0 + r) * D + k0 + c4 * 4);
      bf16x4 bv; bv[0] = (bf16)v.x; bv[1] = (bf16)v.y; bv[2] = (bf16)v.z; bv[3] = (bf16)v.w;
      *(bf16x4*)&As[r][c4 * 4] = bv;
    }
    // stage B tile [64][64]
#pragma unroll
    for (int i = 0; i < 4; ++i) {
      int idx = i * 256 + tid;
      int r = idx >> 4, c4 = idx & 15;
      const float4 v = *(const float4*)(Bm + (size_t)(n0 + r) * D + k0 + c4 * 4);
      bf16x4 bv; bv[0] = (bf16)v.x; bv[1] = (bf16)v.y; bv[2] = (bf16)v.z; bv[3] = (bf16)v.w;
      *(bf16x4*)&Bs[r][c4 * 4] = bv;
    }
    __syncthreads();
#pragma unroll
    for (int kc = 0; kc < 2; ++kc) {
      const int ko = kc * 32 + (lane >> 4) * 8;
      bf16x8 a[4];
#pragma unroll
      for (int mf = 0; mf < 4; ++mf)
        a[mf] = *(bf16x8*)&As[wr * 64 + mf * 16 + (lane & 15)][ko];
#pragma unroll
      for (int nf = 0; nf < 2; ++nf) {
        bf16x8 bb = *(bf16x8*)&Bs[wc * 32 + nf * 16 + (lane & 15)][ko];
#pragma unroll
        for (int mf = 0; mf < 4; ++mf) acc[mf][nf] = mfma16(a[mf], bb, acc[mf][nf]);
      }
    }
  }

  // epilogue: C/D frag: col = lane&15, row = (lane>>4)*4 + r
#pragma unroll
  for (int nf = 0; nf < 2; ++nf) {
    const int col = n0 + wc * 32 + nf * 16 + (lane & 15);
    float bcol = 0.f;
    if constexpr (MODE != 2) bcol = bias[col];
#pragma unroll
    for (int mf = 0; mf < 4; ++mf) {
#pragma unroll
      for (int r = 0; r < 4; ++r) {
        const int row = m0 + wr * 64 + mf * 16 + (lane >> 4) * 4 + r;
        float v = acc[mf][nf][r];
        if constexpr (MODE == 0) {
          v += bcol;
          outF[(size_t)row * D + col] = v;
          out1[(size_t)row * D + col] = (bf16)v;
          out2[(size_t)row * D + col] = (bf16)tanhf(v);
        } else if constexpr (MODE == 1) {
          v += bcol;
          out1[(size_t)row * D + col] = (bf16)v;
          out2[(size_t)row * D + col] = (bf16)tanhf(v);
        } else {
          v += bias[row];  // row = dk
          // Vt layout: [b][dk][m_local], col = global m = b*4096 + m_local
          out1[(size_t)(col >> 12) * (256 * 4096) + (size_t)row * 4096 + (col & 4095)] = (bf16)v;
        }
      }
    }
  }
}

// ---------------------------------------------------------------------------
// Scores: per batch, e = exp( (Q K^T) * ((tanhQ tanhK^T + 1)*0.5) / 16 )
// written to attn region; deterministic partial row sums -> partials[row][mt].
// Tile BM=128 (n) x BN=64 (m), BK=64, dual GEMM, 256 threads (4 waves 2x2).
// ---------------------------------------------------------------------------
__global__ __launch_bounds__(256)
void scores_kernel(const bf16* __restrict__ Qb, const bf16* __restrict__ tQb,
                   const bf16* __restrict__ Kb, const bf16* __restrict__ tKb,
                   float* __restrict__ attn, float* __restrict__ partials)
{
  __shared__ bf16 Qs[128][64], tQs[128][64];
  __shared__ bf16 Ks[64][64],  tKs[64][64];
  __shared__ float rowpart[128][2];
  const int tid = threadIdx.x, lane = tid & 63, wid = tid >> 6;
  const int wr = wid >> 1, wc = wid & 1;
  const int mt = blockIdx.x, nt = blockIdx.y, b = blockIdx.z;
  const int RQ = b * N2 + nt * 128;
  const int RK = b * N1 + mt * 64;

  f32x4 accS[4][2], accP[4][2];
#pragma unroll
  for (int i = 0; i < 4; ++i)
#pragma unroll
    for (int j = 0; j < 2; ++j) {
      accS[i][j] = f32x4{0.f, 0.f, 0.f, 0.f};
      accP[i][j] = f32x4{0.f, 0.f, 0.f, 0.f};
    }

  for (int kt = 0; kt < 4; ++kt) {
    const int k0 = kt * 64;
    if (kt) __syncthreads();
    // Q-side tiles: 16 segments of 1KB each
#pragma unroll
    for (int i = 0; i < 4; ++i) {
      int seg = wid + i * 4;
      int chunk = seg * 64 + lane;
      int row = chunk >> 3, off = (chunk & 7) * 8;
      gload_lds16(Qb  + (size_t)(RQ + row) * D + k0 + off, (char*)&Qs[0][0]  + seg * 1024);
      gload_lds16(tQb + (size_t)(RQ + row) * D + k0 + off, (char*)&tQs[0][0] + seg * 1024);
    }
    // K-side tiles: 8 segments
#pragma unroll
    for (int i = 0; i < 2; ++i) {
      int seg = wid + i * 4;
      int chunk = seg * 64 + lane;
      int row = chunk >> 3, off = (chunk & 7) * 8;
      gload_lds16(Kb  + (size_t)(RK + row) * D + k0 + off, (char*)&Ks[0][0]  + seg * 1024);
      gload_lds16(tKb + (size_t)(RK + row) * D + k0 + off, (char*)&tKs[0][0] + seg * 1024);
    }
    __syncthreads();
#pragma unroll
    for (int kc = 0; kc < 2; ++kc) {
      const int ko = kc * 32 + (lane >> 4) * 8;
      bf16x8 aS[4], aT[4];
#pragma unroll
      for (int mf = 0; mf < 4; ++mf) {
        aS[mf] = *(bf16x8*)&Qs[wr * 64 + mf * 16 + (lane & 15)][ko];
        aT[mf] = *(bf16x8*)&tQs[wr * 64 + mf * 16 + (lane & 15)][ko];
      }
#pragma unroll
      for (int nf = 0; nf < 2; ++nf) {
        bf16x8 bS = *(bf16x8*)&Ks[wc * 32 + nf * 16 + (lane & 15)][ko];
        bf16x8 bT = *(bf16x8*)&tKs[wc * 32 + nf * 16 + (lane & 15)][ko];
#pragma unroll
        for (int mf = 0; mf < 4; ++mf) {
          accS[mf][nf] = mfma16(aS[mf], bS, accS[mf][nf]);
          accP[mf][nf] = mfma16(aT[mf], bT, accP[mf][nf]);
        }
      }
    }
  }

  // epilogue: s = S*(P+1)*0.5/16; e = exp(s); store e; row-sum partials
#pragma unroll
  for (int mf = 0; mf < 4; ++mf) {
    f32x4 rs = f32x4{0.f, 0.f, 0.f, 0.f};
#pragma unroll
    for (int nf = 0; nf < 2; ++nf) {
      const int m_g = mt * 64 + wc * 32 + nf * 16 + (lane & 15);
#pragma unroll
      for (int r = 0; r < 4; ++r) {
        const int n_g = b * N2 + nt * 128 + wr * 64 + mf * 16 + (lane >> 4) * 4 + r;
        float s = accS[mf][nf][r] * (accP[mf][nf][r] + 1.0f) * 0.03125f;
        float e = __expf(s);
        attn[(size_t)n_g * N1 + m_g] = e;
        rs[r] += e;
      }
    }
#pragma unroll
    for (int r = 0; r < 4; ++r) {
      float v = rs[r];
      v += __shfl_xor(v, 1); v += __shfl_xor(v, 2);
      v += __shfl_xor(v, 4); v += __shfl_xor(v, 8);
      if ((lane & 15) == 0)
        rowpart[wr * 64 + mf * 16 + (lane >> 4) * 4 + r][wc] = v;
    }
  }
  __syncthreads();
  if (tid < 128) {
    float p = rowpart[tid][0] + rowpart[tid][1];
    partials[(size_t)(b * N2 + nt * 128 + tid) * 64 + mt] = p;
  }
}

// ---------------------------------------------------------------------------
// Row-sum reduce: rinv[row] = 1 / sum_j partials[row][j]
// ---------------------------------------------------------------------------
__global__ __launch_bounds__(256)
void rowsum_kernel(const float* __restrict__ partials, float* __restrict__ rinv)
{
  int r = blockIdx.x * 256 + threadIdx.x;
  float s = 0.f;
#pragma unroll
  for (int j = 0; j < 64; ++j) s += partials[(size_t)r * 64 + j];
  rinv[r] = 1.0f / s;
}

// ---------------------------------------------------------------------------
// Q_hat = attn @ V; also finalizes attn in-place (attn = e * rinv[row]).
// Per batch: M=2048(n) x N=256(dk), K=4096(m). BM=32, BN=256, BK=64.
// 512 threads (8 waves), wave tile 32x32.
// ---------------------------------------------------------------------------
__global__ __launch_bounds__(512)
void qhat_kernel(float* __restrict__ attn, const bf16* __restrict__ Vt,
                 const float* __restrict__ rinv, float* __restrict__ Qhat)
{
  __shared__ bf16 As[32][64];
  __shared__ bf16 Bs[256][64];
  const int tid = threadIdx.x, lane = tid & 63, wid = tid >> 6;
  const int n0 = blockIdx.x * 32, b = blockIdx.y;
  const int arow = tid >> 4, ac4 = tid & 15;
  const float inv = rinv[b * N2 + n0 + arow];
  float* aptr = attn + (size_t)(b * N2 + n0 + arow) * N1;
  const bf16* vbase = Vt + (size_t)b * (256 * 4096);

  f32x4 acc[2][2];
#pragma unroll
  for (int i = 0; i < 2; ++i)
#pragma unroll
    for (int j = 0; j < 2; ++j) acc[i][j] = f32x4{0.f, 0.f, 0.f, 0.f};

  for (int kt = 0; kt < 64; ++kt) {
    const int k0 = kt * 64;
    if (kt) __syncthreads();
    // stage A: read e, scale -> final attn (write back), convert to bf16
    {
      float4 v = *(const float4*)(aptr + k0 + ac4 * 4);
      v.x *= inv; v.y *= inv; v.z *= inv; v.w *= inv;
      *(float4*)(aptr + k0 + ac4 * 4) = v;
      bf16x4 bv; bv[0] = (bf16)v.x; bv[1] = (bf16)v.y; bv[2] = (bf16)v.z; bv[3] = (bf16)v.w;
      *(bf16x4*)&As[arow][ac4 * 4] = bv;
    }
    // stage B: Vt slice [256 dk][64 m] via global_load_lds (32 segments)
#pragma unroll
    for (int i = 0; i < 4; ++i) {
      int seg = wid + i * 8;
      int chunk = seg * 64 + lane;
      int row = chunk >> 3, off = (chunk & 7) * 8;
      gload_lds16(vbase + (size_t)row * 4096 + k0 + off, (char*)&Bs[0][0] + seg * 1024);
    }
    __syncthreads();
#pragma unroll
    for (int kc = 0; kc < 2; ++kc) {
      const int ko = kc * 32 + (lane >> 4) * 8;
      bf16x8 a0 = *(bf16x8*)&As[(lane & 15)][ko];
      bf16x8 a1 = *(bf16x8*)&As[16 + (lane & 15)][ko];
#pragma unroll
      for (int nf = 0; nf < 2; ++nf) {
        bf16x8 bb = *(bf16x8*)&Bs[wid * 32 + nf * 16 + (lane & 15)][ko];
        acc[0][nf] = mfma16(a0, bb, acc[0][nf]);
        acc[1][nf] = mfma16(a1, bb, acc[1][nf]);
      }
    }
  }

#pragma unroll
  for (int mf = 0; mf < 2; ++mf)
#pragma unroll
    for (int nf = 0; nf < 2; ++nf)
#pragma unroll
      for (int r = 0; r < 4; ++r) {
        const int n = n0 + mf * 16 + (lane >> 4) * 4 + r;
        const int col = wid * 32 + nf * 16 + (lane & 15);
        Qhat[(size_t)(b * N2 + n) * D + col] = acc[mf][nf][r];
      }
}

// ---------------------------------------------------------------------------
extern "C" void kernel_launch(void* const* d_in, const int* in_sizes, int n_in,
                              void* d_out, int out_size, void* d_ws, size_t ws_size,
                              hipStream_t stream)
{
  const float* x1 = (const float*)d_in[0];
  const float* x2 = (const float*)d_in[1];
  const float* WQ = (const float*)d_in[2];
  const float* bQ = (const float*)d_in[3];
  const float* WK = (const float*)d_in[4];
  const float* bK = (const float*)d_in[5];
  const float* WV = (const float*)d_in[6];
  const float* bV = (const float*)d_in[7];

  float* out  = (float*)d_out;
  float* Qf   = out;                    // [4,2048,256]
  float* Qhat = out + 2097152;          // [4,2048,256]
  float* attn = out + 4194304;          // [4,2048,4096]

  char* ws = (char*)d_ws;
  bf16* Qb   = (bf16*)(ws + (0ull  << 20));  // 4 MB
  bf16* tQb  = (bf16*)(ws + (4ull  << 20));  // 4 MB
  bf16* Kb   = (bf16*)(ws + (8ull  << 20));  // 8 MB
  bf16* tKb  = (bf16*)(ws + (16ull << 20));  // 8 MB
  bf16* Vt   = (bf16*)(ws + (24ull << 20));  // 8 MB  [b][dk][m]
  float* partials = (float*)(ws + (32ull << 20));  // 8192*64*4 = 2 MB
  float* rinv     = (float*)(ws + (34ull << 20));  // 32 KB

  proj_kernel<0><<<dim3(64, 4),   256, 0, stream>>>(x2, WQ, bQ, Qf, Qb, tQb);
  proj_kernel<1><<<dim3(128, 4),  256, 0, stream>>>(x1, WK, bK, nullptr, Kb, tKb);
  proj_kernel<2><<<dim3(2, 256),  256, 0, stream>>>(WV, x1, bV, nullptr, Vt, nullptr);
  scores_kernel<<<dim3(64, 16, 4), 256, 0, stream>>>(Qb, tQb, Kb, tKb, attn, partials);
  rowsum_kernel<<<32, 256, 0, stream>>>(partials, rinv);
  qhat_kernel<<<dim3(64, 4), 512, 0, stream>>>(attn, Vt, rinv, Qhat);
}

// Round 2
// 207.816 us; speedup vs baseline: 1.0832x; 1.0832x over previous
//
#include <hip/hip_runtime.h>
#include <hip/hip_bf16.h>

typedef __bf16 bf16;
typedef __bf16 bf16x4 __attribute__((ext_vector_type(4)));
typedef __bf16 bf16x8 __attribute__((ext_vector_type(8)));
typedef float  f32x4  __attribute__((ext_vector_type(4)));

#define DEVI static __device__ __forceinline__

constexpr int NB = 4;
constexpr int N1 = 4096;
constexpr int N2 = 2048;
constexpr int D  = 256;   // DIM1 = DIM2 = DK

DEVI f32x4 mfma16(bf16x8 a, bf16x8 b, f32x4 c) {
  return __builtin_amdgcn_mfma_f32_16x16x32_bf16(a, b, c, 0, 0, 0);
}

typedef const __attribute__((address_space(1))) void* gas_t;
typedef __attribute__((address_space(3))) void* las_t;

DEVI void gload_lds16(const void* g, void* l) {
  __builtin_amdgcn_global_load_lds((gas_t)g, (las_t)l, 16, 0, 0);
}

// ---------------------------------------------------------------------------
// Q projection with hi/lo bf16 split for near-fp32 accuracy on the fp32 Q out.
// C[M,N] = A[M,256] * B[N,256]^T + bias.  A=x2 (M=8192), B=WQ (N=256).
// Outputs: Qf fp32, Qb bf16, tQb bf16.
// Tile BM=128, BN=64, BK=64; 256 threads (4 waves 2x2).
// ---------------------------------------------------------------------------
__global__ __launch_bounds__(256)
void projQ_kernel(const float* __restrict__ A, const float* __restrict__ Bm,
                  const float* __restrict__ bias,
                  float* __restrict__ outF, bf16* __restrict__ out1,
                  bf16* __restrict__ out2)
{
  __shared__ bf16 Ah[128][64], Al[128][64];
  __shared__ bf16 Bh[64][64],  Bl[64][64];
  const int tid  = threadIdx.x;
  const int lane = tid & 63, wid = tid >> 6;
  const int wr = wid >> 1, wc = wid & 1;
  const int m0 = blockIdx.x * 128, n0 = blockIdx.y * 64;

  f32x4 acc[4][2];
#pragma unroll
  for (int i = 0; i < 4; ++i)
#pragma unroll
    for (int j = 0; j < 2; ++j) acc[i][j] = f32x4{0.f, 0.f, 0.f, 0.f};

  for (int kt = 0; kt < 4; ++kt) {
    const int k0 = kt * 64;
    if (kt) __syncthreads();
#pragma unroll
    for (int i = 0; i < 8; ++i) {
      int idx = i * 256 + tid;
      int r = idx >> 4, c4 = idx & 15;
      const float4 v = *(const float4*)(A + (size_t)(m0 + r) * D + k0 + c4 * 4);
      bf16x4 h, l;
      h[0] = (bf16)v.x; h[1] = (bf16)v.y; h[2] = (bf16)v.z; h[3] = (bf16)v.w;
      l[0] = (bf16)(v.x - (float)h[0]); l[1] = (bf16)(v.y - (float)h[1]);
      l[2] = (bf16)(v.z - (float)h[2]); l[3] = (bf16)(v.w - (float)h[3]);
      *(bf16x4*)&Ah[r][c4 * 4] = h;
      *(bf16x4*)&Al[r][c4 * 4] = l;
    }
#pragma unroll
    for (int i = 0; i < 4; ++i) {
      int idx = i * 256 + tid;
      int r = idx >> 4, c4 = idx & 15;
      const float4 v = *(const float4*)(Bm + (size_t)(n0 + r) * D + k0 + c4 * 4);
      bf16x4 h, l;
      h[0] = (bf16)v.x; h[1] = (bf16)v.y; h[2] = (bf16)v.z; h[3] = (bf16)v.w;
      l[0] = (bf16)(v.x - (float)h[0]); l[1] = (bf16)(v.y - (float)h[1]);
      l[2] = (bf16)(v.z - (float)h[2]); l[3] = (bf16)(v.w - (float)h[3]);
      *(bf16x4*)&Bh[r][c4 * 4] = h;
      *(bf16x4*)&Bl[r][c4 * 4] = l;
    }
    __syncthreads();
#pragma unroll
    for (int kc = 0; kc < 2; ++kc) {
      const int ko = kc * 32 + (lane >> 4) * 8;
      bf16x8 ah[4], al[4];
#pragma unroll
      for (int mf = 0; mf < 4; ++mf) {
        ah[mf] = *(bf16x8*)&Ah[wr * 64 + mf * 16 + (lane & 15)][ko];
        al[mf] = *(bf16x8*)&Al[wr * 64 + mf * 16 + (lane & 15)][ko];
      }
#pragma unroll
      for (int nf = 0; nf < 2; ++nf) {
        bf16x8 bh = *(bf16x8*)&Bh[wc * 32 + nf * 16 + (lane & 15)][ko];
        bf16x8 bl = *(bf16x8*)&Bl[wc * 32 + nf * 16 + (lane & 15)][ko];
#pragma unroll
        for (int mf = 0; mf < 4; ++mf) {
          acc[mf][nf] = mfma16(ah[mf], bh, acc[mf][nf]);
          acc[mf][nf] = mfma16(ah[mf], bl, acc[mf][nf]);
          acc[mf][nf] = mfma16(al[mf], bh, acc[mf][nf]);
        }
      }
    }
  }

#pragma unroll
  for (int nf = 0; nf < 2; ++nf) {
    const int col = n0 + wc * 32 + nf * 16 + (lane & 15);
    const float bcol = bias[col];
#pragma unroll
    for (int mf = 0; mf < 4; ++mf) {
#pragma unroll
      for (int r = 0; r < 4; ++r) {
        const int row = m0 + wr * 64 + mf * 16 + (lane >> 4) * 4 + r;
        float v = acc[mf][nf][r] + bcol;
        outF[(size_t)row * D + col] = v;
        out1[(size_t)row * D + col] = (bf16)v;
        out2[(size_t)row * D + col] = (bf16)tanhf(v);
      }
    }
  }
}

// ---------------------------------------------------------------------------
// K / V^T projections (plain bf16 MFMA).
// MODE 1 (K): A=x1 M=16384, B=WK.  out: Kb bf16, tanh(K) bf16.
// MODE 2 (V^T): A=WV M=256, B=x1 N=16384, bias per-row. out: Vt bf16 [b][dk][m].
// ---------------------------------------------------------------------------
template<int MODE>
__global__ __launch_bounds__(256)
void proj_kernel(const float* __restrict__ A, const float* __restrict__ Bm,
                 const float* __restrict__ bias,
                 bf16* __restrict__ out1, bf16* __restrict__ out2)
{
  __shared__ bf16 As[128][64];
  __shared__ bf16 Bs[64][64];
  const int tid  = threadIdx.x;
  const int lane = tid & 63, wid = tid >> 6;
  const int wr = wid >> 1, wc = wid & 1;
  const int m0 = blockIdx.x * 128, n0 = blockIdx.y * 64;

  f32x4 acc[4][2];
#pragma unroll
  for (int i = 0; i < 4; ++i)
#pragma unroll
    for (int j = 0; j < 2; ++j) acc[i][j] = f32x4{0.f, 0.f, 0.f, 0.f};

  for (int kt = 0; kt < 4; ++kt) {
    const int k0 = kt * 64;
    if (kt) __syncthreads();
#pragma unroll
    for (int i = 0; i < 8; ++i) {
      int idx = i * 256 + tid;
      int r = idx >> 4, c4 = idx & 15;
      const float4 v = *(const float4*)(A + (size_t)(m0 + r) * D + k0 + c4 * 4);
      bf16x4 bv; bv[0] = (bf16)v.x; bv[1] = (bf16)v.y; bv[2] = (bf16)v.z; bv[3] = (bf16)v.w;
      *(bf16x4*)&As[r][c4 * 4] = bv;
    }
#pragma unroll
    for (int i = 0; i < 4; ++i) {
      int idx = i * 256 + tid;
      int r = idx >> 4, c4 = idx & 15;
      const float4 v = *(const float4*)(Bm + (size_t)(n0 + r) * D + k0 + c4 * 4);
      bf16x4 bv; bv[0] = (bf16)v.x; bv[1] = (bf16)v.y; bv[2] = (bf16)v.z; bv[3] = (bf16)v.w;
      *(bf16x4*)&Bs[r][c4 * 4] = bv;
    }
    __syncthreads();
#pragma unroll
    for (int kc = 0; kc < 2; ++kc) {
      const int ko = kc * 32 + (lane >> 4) * 8;
      bf16x8 a[4];
#pragma unroll
      for (int mf = 0; mf < 4; ++mf)
        a[mf] = *(bf16x8*)&As[wr * 64 + mf * 16 + (lane & 15)][ko];
#pragma unroll
      for (int nf = 0; nf < 2; ++nf) {
        bf16x8 bb = *(bf16x8*)&Bs[wc * 32 + nf * 16 + (lane & 15)][ko];
#pragma unroll
        for (int mf = 0; mf < 4; ++mf) acc[mf][nf] = mfma16(a[mf], bb, acc[mf][nf]);
      }
    }
  }

#pragma unroll
  for (int nf = 0; nf < 2; ++nf) {
    const int col = n0 + wc * 32 + nf * 16 + (lane & 15);
    float bcol = 0.f;
    if constexpr (MODE == 1) bcol = bias[col];
#pragma unroll
    for (int mf = 0; mf < 4; ++mf) {
#pragma unroll
      for (int r = 0; r < 4; ++r) {
        const int row = m0 + wr * 64 + mf * 16 + (lane >> 4) * 4 + r;
        float v = acc[mf][nf][r];
        if constexpr (MODE == 1) {
          v += bcol;
          out1[(size_t)row * D + col] = (bf16)v;
          out2[(size_t)row * D + col] = (bf16)tanhf(v);
        } else {
          v += bias[row];  // row = dk
          out1[(size_t)(col >> 12) * (D * N1) + (size_t)row * N1 + (col & 4095)] = (bf16)v;
        }
      }
    }
  }
}

// ---------------------------------------------------------------------------
// Scores: e = exp( (Q K^T) * ((tanhQ tanhK^T + 1)*0.5) / 16 ) -> E (bf16);
// deterministic partial row sums (fp32 e) -> partials[row][mt].
// ---------------------------------------------------------------------------
__global__ __launch_bounds__(256)
void scores_kernel(const bf16* __restrict__ Qb, const bf16* __restrict__ tQb,
                   const bf16* __restrict__ Kb, const bf16* __restrict__ tKb,
                   bf16* __restrict__ E, float* __restrict__ partials)
{
  __shared__ bf16 Qs[128][64], tQs[128][64];
  __shared__ bf16 Ks[64][64],  tKs[64][64];
  __shared__ float rowpart[128][2];
  const int tid = threadIdx.x, lane = tid & 63, wid = tid >> 6;
  const int wr = wid >> 1, wc = wid & 1;
  const int mt = blockIdx.x, nt = blockIdx.y, b = blockIdx.z;
  const int RQ = b * N2 + nt * 128;
  const int RK = b * N1 + mt * 64;

  f32x4 accS[4][2], accP[4][2];
#pragma unroll
  for (int i = 0; i < 4; ++i)
#pragma unroll
    for (int j = 0; j < 2; ++j) {
      accS[i][j] = f32x4{0.f, 0.f, 0.f, 0.f};
      accP[i][j] = f32x4{0.f, 0.f, 0.f, 0.f};
    }

  for (int kt = 0; kt < 4; ++kt) {
    const int k0 = kt * 64;
    if (kt) __syncthreads();
#pragma unroll
    for (int i = 0; i < 4; ++i) {
      int seg = wid + i * 4;
      int chunk = seg * 64 + lane;
      int row = chunk >> 3, off = (chunk & 7) * 8;
      gload_lds16(Qb  + (size_t)(RQ + row) * D + k0 + off, (char*)&Qs[0][0]  + seg * 1024);
      gload_lds16(tQb + (size_t)(RQ + row) * D + k0 + off, (char*)&tQs[0][0] + seg * 1024);
    }
#pragma unroll
    for (int i = 0; i < 2; ++i) {
      int seg = wid + i * 4;
      int chunk = seg * 64 + lane;
      int row = chunk >> 3, off = (chunk & 7) * 8;
      gload_lds16(Kb  + (size_t)(RK + row) * D + k0 + off, (char*)&Ks[0][0]  + seg * 1024);
      gload_lds16(tKb + (size_t)(RK + row) * D + k0 + off, (char*)&tKs[0][0] + seg * 1024);
    }
    __syncthreads();
#pragma unroll
    for (int kc = 0; kc < 2; ++kc) {
      const int ko = kc * 32 + (lane >> 4) * 8;
      bf16x8 aS[4], aT[4];
#pragma unroll
      for (int mf = 0; mf < 4; ++mf) {
        aS[mf] = *(bf16x8*)&Qs[wr * 64 + mf * 16 + (lane & 15)][ko];
        aT[mf] = *(bf16x8*)&tQs[wr * 64 + mf * 16 + (lane & 15)][ko];
      }
#pragma unroll
      for (int nf = 0; nf < 2; ++nf) {
        bf16x8 bS = *(bf16x8*)&Ks[wc * 32 + nf * 16 + (lane & 15)][ko];
        bf16x8 bT = *(bf16x8*)&tKs[wc * 32 + nf * 16 + (lane & 15)][ko];
#pragma unroll
        for (int mf = 0; mf < 4; ++mf) {
          accS[mf][nf] = mfma16(aS[mf], bS, accS[mf][nf]);
          accP[mf][nf] = mfma16(aT[mf], bT, accP[mf][nf]);
        }
      }
    }
  }

#pragma unroll
  for (int mf = 0; mf < 4; ++mf) {
    f32x4 rs = f32x4{0.f, 0.f, 0.f, 0.f};
#pragma unroll
    for (int nf = 0; nf < 2; ++nf) {
      const int m_g = mt * 64 + wc * 32 + nf * 16 + (lane & 15);
#pragma unroll
      for (int r = 0; r < 4; ++r) {
        const int n_g = b * N2 + nt * 128 + wr * 64 + mf * 16 + (lane >> 4) * 4 + r;
        float s = accS[mf][nf][r] * (accP[mf][nf][r] + 1.0f) * 0.03125f;
        float e = __expf(s);
        E[(size_t)n_g * N1 + m_g] = (bf16)e;
        rs[r] += e;
      }
    }
#pragma unroll
    for (int r = 0; r < 4; ++r) {
      float v = rs[r];
      v += __shfl_xor(v, 1); v += __shfl_xor(v, 2);
      v += __shfl_xor(v, 4); v += __shfl_xor(v, 8);
      if ((lane & 15) == 0)
        rowpart[wr * 64 + mf * 16 + (lane >> 4) * 4 + r][wc] = v;
    }
  }
  __syncthreads();
  if (tid < 128) {
    float p = rowpart[tid][0] + rowpart[tid][1];
    partials[(size_t)(b * N2 + nt * 128 + tid) * 64 + mt] = p;
  }
}

// ---------------------------------------------------------------------------
__global__ __launch_bounds__(256)
void rowsum_kernel(const float* __restrict__ partials, float* __restrict__ rinv)
{
  int r = blockIdx.x * 256 + threadIdx.x;
  float s = 0.f;
#pragma unroll
  for (int j = 0; j < 64; ++j) s += partials[(size_t)r * 64 + j];
  rinv[r] = 1.0f / s;
}

// ---------------------------------------------------------------------------
// Q_hat partial = (E*rinv) @ V over an m-quarter; also writes final attn fp32.
// Grid (32 ntiles, 4 m-quarters, 4 batches), 512 threads (8 waves, dk-split).
// BM=64 n, BN=256 dk, m-step 64.
// ---------------------------------------------------------------------------
__global__ __launch_bounds__(512)
void qhat_kernel(const bf16* __restrict__ E, const bf16* __restrict__ Vt,
                 const float* __restrict__ rinv,
                 float* __restrict__ attn, float* __restrict__ partQ)
{
  __shared__ bf16 As[64][64];
  __shared__ bf16 Bs[256][64];
  const int tid = threadIdx.x, lane = tid & 63, wid = tid >> 6;
  const int n0 = blockIdx.x * 64;
  const int mh = blockIdx.y;
  const int b  = blockIdx.z;
  const int m_base = mh * 1024;
  const int arow = tid >> 3;          // 0..63
  const int mo   = (tid & 7) * 8;     // 0..56
  const size_t rglob = (size_t)b * N2 + n0 + arow;
  const float inv = rinv[rglob];
  const bf16* erow  = E    + rglob * N1 + m_base;
  float*      aorow = attn + rglob * N1 + m_base;
  const bf16* vbase = Vt + (size_t)b * (D * N1) + m_base;
  const int vdk = tid >> 3;           // staging dk within 64-group

  f32x4 acc[4][2];
#pragma unroll
  for (int i = 0; i < 4; ++i)
#pragma unroll
    for (int j = 0; j < 2; ++j) acc[i][j] = f32x4{0.f, 0.f, 0.f, 0.f};

  for (int ms = 0; ms < 16; ++ms) {
    if (ms) __syncthreads();
    // A stage: read e (bf16), scale -> write final attn fp32, stash scaled bf16
    {
      bf16x8 ev = *(const bf16x8*)(erow + ms * 64 + mo);
      float v[8];
      bf16x8 sv;
#pragma unroll
      for (int j = 0; j < 8; ++j) { v[j] = (float)ev[j] * inv; sv[j] = (bf16)v[j]; }
      float4 w0 = {v[0], v[1], v[2], v[3]};
      float4 w1 = {v[4], v[5], v[6], v[7]};
      *(float4*)(aorow + ms * 64 + mo)     = w0;
      *(float4*)(aorow + ms * 64 + mo + 4) = w1;
      *(bf16x8*)&As[arow][mo] = sv;
    }
    // B stage: Vt slice [256 dk][64 m] via global_load_lds, 4 x 8KB
#pragma unroll
    for (int i = 0; i < 4; ++i) {
      int dk = i * 64 + vdk;
      gload_lds16(vbase + (size_t)dk * N1 + ms * 64 + mo,
                  (char*)&Bs[0][0] + i * 8192 + tid * 16);
    }
    __syncthreads();
#pragma unroll
    for (int kc = 0; kc < 2; ++kc) {
      const int ko = kc * 32 + (lane >> 4) * 8;
      bf16x8 a[4];
#pragma unroll
      for (int mf = 0; mf < 4; ++mf)
        a[mf] = *(bf16x8*)&As[mf * 16 + (lane & 15)][ko];
#pragma unroll
      for (int nf = 0; nf < 2; ++nf) {
        bf16x8 bb = *(bf16x8*)&Bs[wid * 32 + nf * 16 + (lane & 15)][ko];
#pragma unroll
        for (int mf = 0; mf < 4; ++mf) acc[mf][nf] = mfma16(a[mf], bb, acc[mf][nf]);
      }
    }
  }

#pragma unroll
  for (int mf = 0; mf < 4; ++mf)
#pragma unroll
    for (int nf = 0; nf < 2; ++nf)
#pragma unroll
      for (int r = 0; r < 4; ++r) {
        const int n  = n0 + mf * 16 + (lane >> 4) * 4 + r;
        const int dk = wid * 32 + nf * 16 + (lane & 15);
        partQ[((size_t)(mh * NB + b) * N2 + n) * D + dk] = acc[mf][nf][r];
      }
}

// ---------------------------------------------------------------------------
__global__ __launch_bounds__(256)
void reduceQ_kernel(const float* __restrict__ P, float* __restrict__ Qhat)
{
  const size_t i = ((size_t)blockIdx.x * 256 + threadIdx.x) * 4;
  const size_t S = (size_t)NB * N2 * D;
  f32x4 s = *(const f32x4*)(P + i);
  s += *(const f32x4*)(P + S + i);
  s += *(const f32x4*)(P + 2 * S + i);
  s += *(const f32x4*)(P + 3 * S + i);
  *(f32x4*)(Qhat + i) = s;
}

// ---------------------------------------------------------------------------
extern "C" void kernel_launch(void* const* d_in, const int* in_sizes, int n_in,
                              void* d_out, int out_size, void* d_ws, size_t ws_size,
                              hipStream_t stream)
{
  const float* x1 = (const float*)d_in[0];
  const float* x2 = (const float*)d_in[1];
  const float* WQ = (const float*)d_in[2];
  const float* bQ = (const float*)d_in[3];
  const float* WK = (const float*)d_in[4];
  const float* bK = (const float*)d_in[5];
  const float* WV = (const float*)d_in[6];
  const float* bV = (const float*)d_in[7];

  float* out  = (float*)d_out;
  float* Qf   = out;                    // [4,2048,256]
  float* Qhat = out + 2097152;          // [4,2048,256]
  float* attn = out + 4194304;          // [4,2048,4096]

  char* ws = (char*)d_ws;
  bf16* Qb   = (bf16*)(ws + (0ull  << 20));  // 4 MB
  bf16* tQb  = (bf16*)(ws + (4ull  << 20));  // 4 MB
  bf16* Kb   = (bf16*)(ws + (8ull  << 20));  // 8 MB
  bf16* tKb  = (bf16*)(ws + (16ull << 20));  // 8 MB
  bf16* Vt   = (bf16*)(ws + (24ull << 20));  // 8 MB  [b][dk][m]
  bf16* E    = (bf16*)(ws + (32ull << 20));  // 64 MB [b][n][m] bf16 e
  float* partials = (float*)(ws + (96ull << 20));  // 2 MB
  float* rinv     = (float*)(ws + (98ull << 20));  // 32 KB
  float* partQ    = (float*)(ws + (100ull << 20)); // 32 MB [mh][b][n][dk]

  projQ_kernel    <<<dim3(64, 4),   256, 0, stream>>>(x2, WQ, bQ, Qf, Qb, tQb);
  proj_kernel<1>  <<<dim3(128, 4),  256, 0, stream>>>(x1, WK, bK, Kb, tKb);
  proj_kernel<2>  <<<dim3(2, 256),  256, 0, stream>>>(WV, x1, bV, Vt, nullptr);
  scores_kernel   <<<dim3(64, 16, 4), 256, 0, stream>>>(Qb, tQb, Kb, tKb, E, partials);
  rowsum_kernel   <<<32, 256, 0, stream>>>(partials, rinv);
  qhat_kernel     <<<dim3(32, 4, 4), 512, 0, stream>>>(E, Vt, rinv, attn, partQ);
  reduceQ_kernel  <<<2048, 256, 0, stream>>>(partQ, Qhat);
}

// Round 3
// 190.404 us; speedup vs baseline: 1.1822x; 1.0914x over previous
//
#include <hip/hip_runtime.h>
#include <hip/hip_bf16.h>

typedef __bf16 bf16;
typedef __bf16 bf16x4 __attribute__((ext_vector_type(4)));
typedef __bf16 bf16x8 __attribute__((ext_vector_type(8)));
typedef float  f32x4  __attribute__((ext_vector_type(4)));

#define DEVI static __device__ __forceinline__

constexpr int NB = 4;
constexpr int N1 = 4096;
constexpr int N2 = 2048;
constexpr int D  = 256;   // DIM1 = DIM2 = DK

DEVI f32x4 mfma16(bf16x8 a, bf16x8 b, f32x4 c) {
  return __builtin_amdgcn_mfma_f32_16x16x32_bf16(a, b, c, 0, 0, 0);
}

typedef const __attribute__((address_space(1))) void* gas_t;
typedef __attribute__((address_space(3))) void* las_t;

DEVI void gload_lds16(const void* g, void* l) {
  __builtin_amdgcn_global_load_lds((gas_t)g, (las_t)l, 16, 0, 0);
}

// ---------------------------------------------------------------------------
// Q projection with hi/lo bf16 split for near-fp32 accuracy on the fp32 Q out.
// ---------------------------------------------------------------------------
__global__ __launch_bounds__(256)
void projQ_kernel(const float* __restrict__ A, const float* __restrict__ Bm,
                  const float* __restrict__ bias,
                  float* __restrict__ outF, bf16* __restrict__ out1,
                  bf16* __restrict__ out2)
{
  __shared__ bf16 Ah[128][64], Al[128][64];
  __shared__ bf16 Bh[64][64],  Bl[64][64];
  const int tid  = threadIdx.x;
  const int lane = tid & 63, wid = tid >> 6;
  const int wr = wid >> 1, wc = wid & 1;
  const int m0 = blockIdx.x * 128, n0 = blockIdx.y * 64;

  f32x4 acc[4][2];
#pragma unroll
  for (int i = 0; i < 4; ++i)
#pragma unroll
    for (int j = 0; j < 2; ++j) acc[i][j] = f32x4{0.f, 0.f, 0.f, 0.f};

  for (int kt = 0; kt < 4; ++kt) {
    const int k0 = kt * 64;
    if (kt) __syncthreads();
#pragma unroll
    for (int i = 0; i < 8; ++i) {
      int idx = i * 256 + tid;
      int r = idx >> 4, c4 = idx & 15;
      const float4 v = *(const float4*)(A + (size_t)(m0 + r) * D + k0 + c4 * 4);
      bf16x4 h, l;
      h[0] = (bf16)v.x; h[1] = (bf16)v.y; h[2] = (bf16)v.z; h[3] = (bf16)v.w;
      l[0] = (bf16)(v.x - (float)h[0]); l[1] = (bf16)(v.y - (float)h[1]);
      l[2] = (bf16)(v.z - (float)h[2]); l[3] = (bf16)(v.w - (float)h[3]);
      *(bf16x4*)&Ah[r][c4 * 4] = h;
      *(bf16x4*)&Al[r][c4 * 4] = l;
    }
#pragma unroll
    for (int i = 0; i < 4; ++i) {
      int idx = i * 256 + tid;
      int r = idx >> 4, c4 = idx & 15;
      const float4 v = *(const float4*)(Bm + (size_t)(n0 + r) * D + k0 + c4 * 4);
      bf16x4 h, l;
      h[0] = (bf16)v.x; h[1] = (bf16)v.y; h[2] = (bf16)v.z; h[3] = (bf16)v.w;
      l[0] = (bf16)(v.x - (float)h[0]); l[1] = (bf16)(v.y - (float)h[1]);
      l[2] = (bf16)(v.z - (float)h[2]); l[3] = (bf16)(v.w - (float)h[3]);
      *(bf16x4*)&Bh[r][c4 * 4] = h;
      *(bf16x4*)&Bl[r][c4 * 4] = l;
    }
    __syncthreads();
#pragma unroll
    for (int kc = 0; kc < 2; ++kc) {
      const int ko = kc * 32 + (lane >> 4) * 8;
      bf16x8 ah[4], al[4];
#pragma unroll
      for (int mf = 0; mf < 4; ++mf) {
        ah[mf] = *(bf16x8*)&Ah[wr * 64 + mf * 16 + (lane & 15)][ko];
        al[mf] = *(bf16x8*)&Al[wr * 64 + mf * 16 + (lane & 15)][ko];
      }
#pragma unroll
      for (int nf = 0; nf < 2; ++nf) {
        bf16x8 bh = *(bf16x8*)&Bh[wc * 32 + nf * 16 + (lane & 15)][ko];
        bf16x8 bl = *(bf16x8*)&Bl[wc * 32 + nf * 16 + (lane & 15)][ko];
#pragma unroll
        for (int mf = 0; mf < 4; ++mf) {
          acc[mf][nf] = mfma16(ah[mf], bh, acc[mf][nf]);
          acc[mf][nf] = mfma16(ah[mf], bl, acc[mf][nf]);
          acc[mf][nf] = mfma16(al[mf], bh, acc[mf][nf]);
        }
      }
    }
  }

#pragma unroll
  for (int nf = 0; nf < 2; ++nf) {
    const int col = n0 + wc * 32 + nf * 16 + (lane & 15);
    const float bcol = bias[col];
#pragma unroll
    for (int mf = 0; mf < 4; ++mf) {
#pragma unroll
      for (int r = 0; r < 4; ++r) {
        const int row = m0 + wr * 64 + mf * 16 + (lane >> 4) * 4 + r;
        float v = acc[mf][nf][r] + bcol;
        outF[(size_t)row * D + col] = v;
        out1[(size_t)row * D + col] = (bf16)v;
        out2[(size_t)row * D + col] = (bf16)tanhf(v);
      }
    }
  }
}

// ---------------------------------------------------------------------------
// K / V^T projections (plain bf16 MFMA).
// ---------------------------------------------------------------------------
template<int MODE>
__global__ __launch_bounds__(256)
void proj_kernel(const float* __restrict__ A, const float* __restrict__ Bm,
                 const float* __restrict__ bias,
                 bf16* __restrict__ out1, bf16* __restrict__ out2)
{
  __shared__ bf16 As[128][64];
  __shared__ bf16 Bs[64][64];
  const int tid  = threadIdx.x;
  const int lane = tid & 63, wid = tid >> 6;
  const int wr = wid >> 1, wc = wid & 1;
  const int m0 = blockIdx.x * 128, n0 = blockIdx.y * 64;

  f32x4 acc[4][2];
#pragma unroll
  for (int i = 0; i < 4; ++i)
#pragma unroll
    for (int j = 0; j < 2; ++j) acc[i][j] = f32x4{0.f, 0.f, 0.f, 0.f};

  for (int kt = 0; kt < 4; ++kt) {
    const int k0 = kt * 64;
    if (kt) __syncthreads();
#pragma unroll
    for (int i = 0; i < 8; ++i) {
      int idx = i * 256 + tid;
      int r = idx >> 4, c4 = idx & 15;
      const float4 v = *(const float4*)(A + (size_t)(m0 + r) * D + k0 + c4 * 4);
      bf16x4 bv; bv[0] = (bf16)v.x; bv[1] = (bf16)v.y; bv[2] = (bf16)v.z; bv[3] = (bf16)v.w;
      *(bf16x4*)&As[r][c4 * 4] = bv;
    }
#pragma unroll
    for (int i = 0; i < 4; ++i) {
      int idx = i * 256 + tid;
      int r = idx >> 4, c4 = idx & 15;
      const float4 v = *(const float4*)(Bm + (size_t)(n0 + r) * D + k0 + c4 * 4);
      bf16x4 bv; bv[0] = (bf16)v.x; bv[1] = (bf16)v.y; bv[2] = (bf16)v.z; bv[3] = (bf16)v.w;
      *(bf16x4*)&Bs[r][c4 * 4] = bv;
    }
    __syncthreads();
#pragma unroll
    for (int kc = 0; kc < 2; ++kc) {
      const int ko = kc * 32 + (lane >> 4) * 8;
      bf16x8 a[4];
#pragma unroll
      for (int mf = 0; mf < 4; ++mf)
        a[mf] = *(bf16x8*)&As[wr * 64 + mf * 16 + (lane & 15)][ko];
#pragma unroll
      for (int nf = 0; nf < 2; ++nf) {
        bf16x8 bb = *(bf16x8*)&Bs[wc * 32 + nf * 16 + (lane & 15)][ko];
#pragma unroll
        for (int mf = 0; mf < 4; ++mf) acc[mf][nf] = mfma16(a[mf], bb, acc[mf][nf]);
      }
    }
  }

#pragma unroll
  for (int nf = 0; nf < 2; ++nf) {
    const int col = n0 + wc * 32 + nf * 16 + (lane & 15);
    float bcol = 0.f;
    if constexpr (MODE == 1) bcol = bias[col];
#pragma unroll
    for (int mf = 0; mf < 4; ++mf) {
#pragma unroll
      for (int r = 0; r < 4; ++r) {
        const int row = m0 + wr * 64 + mf * 16 + (lane >> 4) * 4 + r;
        float v = acc[mf][nf][r];
        if constexpr (MODE == 1) {
          v += bcol;
          out1[(size_t)row * D + col] = (bf16)v;
          out2[(size_t)row * D + col] = (bf16)tanhf(v);
        } else {
          v += bias[row];  // row = dk
          out1[(size_t)(col >> 12) * (D * N1) + (size_t)row * N1 + (col & 4095)] = (bf16)v;
        }
      }
    }
  }
}

// ---------------------------------------------------------------------------
// Scores: e = exp( (Q K^T) * ((tanhQ tanhK^T + 1)*0.5) / 16 ) -> E (bf16);
// partial row sums -> partials[row][mt] (mt stride 32).
// Tile 128(n) x 128(m), BK=64, 8 waves (2n x 4m), dbuf LDS + prefetch,
// XOR-swizzled LDS (T2, both-sides).
// ---------------------------------------------------------------------------
__global__ __launch_bounds__(512)
void scores_kernel(const bf16* __restrict__ Qb, const bf16* __restrict__ tQb,
                   const bf16* __restrict__ Kb, const bf16* __restrict__ tKb,
                   bf16* __restrict__ E, float* __restrict__ partials)
{
  __shared__ bf16 SM[2][4][128][64];   // buf, {Qs,tQs,Ks,tKs}
  __shared__ float rowpart[128][4];
  const int tid = threadIdx.x, lane = tid & 63, wid = tid >> 6;
  const int wr = wid >> 2;       // n half (0..1)
  const int wc = wid & 3;        // m quarter (0..3)
  const int lo16 = lane & 15, hi = lane >> 4, sw = lane & 7;
  const int mt = blockIdx.x, nt = blockIdx.y, b = blockIdx.z;
  const int RQ = b * N2 + nt * 128;
  const int RK = b * N1 + mt * 128;

  f32x4 accS[4][2], accP[4][2];
#pragma unroll
  for (int i = 0; i < 4; ++i)
#pragma unroll
    for (int j = 0; j < 2; ++j) {
      accS[i][j] = f32x4{0.f, 0.f, 0.f, 0.f};
      accP[i][j] = f32x4{0.f, 0.f, 0.f, 0.f};
    }

  auto stage = [&](int kt, int buf) {
    const int k0 = kt * 64;
#pragma unroll
    for (int i = 0; i < 2; ++i) {
      const int c = i * 512 + tid;
      const int row = c >> 3;
      const int soff = k0 + (((c & 7) ^ (row & 7)) << 3);  // pre-swizzled source
      char* dst = (char*)&SM[buf][0][0][0] + c * 16;
      gload_lds16(Qb  + (size_t)(RQ + row) * D + soff, dst);
      gload_lds16(tQb + (size_t)(RQ + row) * D + soff, dst + 16384);
      gload_lds16(Kb  + (size_t)(RK + row) * D + soff, dst + 32768);
      gload_lds16(tKb + (size_t)(RK + row) * D + soff, dst + 49152);
    }
  };

  auto cpt = [&](int buf) {
#pragma unroll
    for (int kc = 0; kc < 2; ++kc) {
      const int ko = (((kc * 4 + hi) ^ sw) << 3);  // swizzled read column
      bf16x8 aS[4], aT[4];
#pragma unroll
      for (int mf = 0; mf < 4; ++mf) {
        aS[mf] = *(bf16x8*)&SM[buf][0][wr * 64 + mf * 16 + lo16][ko];
        aT[mf] = *(bf16x8*)&SM[buf][1][wr * 64 + mf * 16 + lo16][ko];
      }
#pragma unroll
      for (int nf = 0; nf < 2; ++nf) {
        bf16x8 bS = *(bf16x8*)&SM[buf][2][wc * 32 + nf * 16 + lo16][ko];
        bf16x8 bT = *(bf16x8*)&SM[buf][3][wc * 32 + nf * 16 + lo16][ko];
#pragma unroll
        for (int mf = 0; mf < 4; ++mf) {
          accS[mf][nf] = mfma16(aS[mf], bS, accS[mf][nf]);
          accP[mf][nf] = mfma16(aT[mf], bT, accP[mf][nf]);
        }
      }
    }
  };

  stage(0, 0);
  __syncthreads();
  int cur = 0;
#pragma unroll
  for (int kt = 0; kt < 4; ++kt) {
    if (kt < 3) stage(kt + 1, cur ^ 1);
    cpt(cur);
    __syncthreads();
    cur ^= 1;
  }

  // epilogue
#pragma unroll
  for (int mf = 0; mf < 4; ++mf) {
    f32x4 rs = f32x4{0.f, 0.f, 0.f, 0.f};
#pragma unroll
    for (int nf = 0; nf < 2; ++nf) {
      const int m_g = mt * 128 + wc * 32 + nf * 16 + lo16;
#pragma unroll
      for (int r = 0; r < 4; ++r) {
        const int n_g = b * N2 + nt * 128 + wr * 64 + mf * 16 + hi * 4 + r;
        float s = accS[mf][nf][r] * (accP[mf][nf][r] + 1.0f) * 0.03125f;
        float e = __expf(s);
        E[(size_t)n_g * N1 + m_g] = (bf16)e;
        rs[r] += e;
      }
    }
#pragma unroll
    for (int r = 0; r < 4; ++r) {
      float v = rs[r];
      v += __shfl_xor(v, 1); v += __shfl_xor(v, 2);
      v += __shfl_xor(v, 4); v += __shfl_xor(v, 8);
      if (lo16 == 0)
        rowpart[wr * 64 + mf * 16 + hi * 4 + r][wc] = v;
    }
  }
  __syncthreads();
  if (tid < 128) {
    float p = rowpart[tid][0] + rowpart[tid][1] + rowpart[tid][2] + rowpart[tid][3];
    partials[(size_t)(b * N2 + nt * 128 + tid) * 32 + mt] = p;
  }
}

// ---------------------------------------------------------------------------
// Q_hat partial = (E*rinv) @ V over an m-quarter; writes final attn fp32.
// rinv computed in-prologue from partials. dbuf LDS (80KB), E reg-prefetch
// depth 2, single barrier per m-step, XOR-swizzled LDS.
// Grid (32 ntiles, 4 m-quarters, 4 batches), 512 threads (8 waves dk-split).
// ---------------------------------------------------------------------------
__global__ __launch_bounds__(512)
void qhat_kernel(const bf16* __restrict__ E, const bf16* __restrict__ Vt,
                 const float* __restrict__ partials,
                 float* __restrict__ attn, float* __restrict__ partQ)
{
  __shared__ bf16 As[2][64][64];
  __shared__ bf16 Bs[2][256][64];
  const int tid = threadIdx.x, lane = tid & 63, wid = tid >> 6;
  const int lo16 = lane & 15, hi = lane >> 4, sw = lane & 7;
  const int n0 = blockIdx.x * 64;
  const int mh = blockIdx.y;
  const int b  = blockIdx.z;
  const int mq = mh * 1024;
  const int arow = tid >> 3;          // 0..63
  const int mo   = (tid & 7) * 8;     // 0..56
  const size_t rglob = (size_t)b * N2 + n0 + arow;

  // rinv: each thread sums its row's 32 partials
  float s = 0.f;
  {
    const float* pr = partials + rglob * 32;
#pragma unroll
    for (int j = 0; j < 32; ++j) s += pr[j];
  }
  const float inv = 1.0f / s;

  const bf16* erow  = E    + rglob * N1 + mq;
  float*      aorow = attn + rglob * N1 + mq;
  const bf16* vbase = Vt + (size_t)b * (D * N1) + mq;
  const int awcol = ((tid & 7) ^ (arow & 7)) << 3;  // swizzled A write col

  f32x4 acc[4][2];
#pragma unroll
  for (int i = 0; i < 4; ++i)
#pragma unroll
    for (int j = 0; j < 2; ++j) acc[i][j] = f32x4{0.f, 0.f, 0.f, 0.f};

  auto loadE = [&](int ms) -> bf16x8 {
    return *(const bf16x8*)(erow + ms * 64 + mo);
  };
  auto stageB = [&](int ms, int buf) {
#pragma unroll
    for (int i = 0; i < 4; ++i) {
      const int c = i * 512 + tid;
      const int row = c >> 3;  // dk 0..255
      gload_lds16(vbase + (size_t)row * N1 + ms * 64 + (((c & 7) ^ (row & 7)) << 3),
                  (char*)&Bs[buf][0][0] + c * 16);
    }
  };
  auto procA = [&](int ms, int buf, bf16x8 e) {
    float v[8]; bf16x8 svv;
#pragma unroll
    for (int j = 0; j < 8; ++j) { v[j] = (float)e[j] * inv; svv[j] = (bf16)v[j]; }
    float4 w0 = {v[0], v[1], v[2], v[3]};
    float4 w1 = {v[4], v[5], v[6], v[7]};
    *(float4*)(aorow + ms * 64 + mo)     = w0;
    *(float4*)(aorow + ms * 64 + mo + 4) = w1;
    *(bf16x8*)((char*)&As[buf][arow][0] + awcol * 2) = svv;
  };
  auto cptq = [&](int buf) {
#pragma unroll
    for (int kc = 0; kc < 2; ++kc) {
      const int ko = (((kc * 4 + hi) ^ sw) << 3);
      bf16x8 a[4];
#pragma unroll
      for (int mf = 0; mf < 4; ++mf)
        a[mf] = *(bf16x8*)&As[buf][mf * 16 + lo16][ko];
#pragma unroll
      for (int nf = 0; nf < 2; ++nf) {
        bf16x8 bb = *(bf16x8*)&Bs[buf][wid * 32 + nf * 16 + lo16][ko];
#pragma unroll
        for (int mf = 0; mf < 4; ++mf) acc[mf][nf] = mfma16(a[mf], bb, acc[mf][nf]);
      }
    }
  };

  bf16x8 ev[2];
  ev[0] = loadE(0);
  stageB(0, 0);
  procA(0, 0, ev[0]);
  ev[1] = loadE(1);
  __syncthreads();

  int cur = 0;
#pragma unroll
  for (int ms = 0; ms < 16; ++ms) {
    if (ms < 15) {
      stageB(ms + 1, cur ^ 1);
      procA(ms + 1, cur ^ 1, ev[(ms + 1) & 1]);
      if (ms < 14) ev[ms & 1] = loadE(ms + 2);
    }
    cptq(cur);
    __syncthreads();
    cur ^= 1;
  }

#pragma unroll
  for (int mf = 0; mf < 4; ++mf)
#pragma unroll
    for (int nf = 0; nf < 2; ++nf)
#pragma unroll
      for (int r = 0; r < 4; ++r) {
        const int n  = n0 + mf * 16 + hi * 4 + r;
        const int dk = wid * 32 + nf * 16 + lo16;
        partQ[((size_t)(mh * NB + b) * N2 + n) * D + dk] = acc[mf][nf][r];
      }
}

// ---------------------------------------------------------------------------
__global__ __launch_bounds__(256)
void reduceQ_kernel(const float* __restrict__ P, float* __restrict__ Qhat)
{
  const size_t i = ((size_t)blockIdx.x * 256 + threadIdx.x) * 4;
  const size_t S = (size_t)NB * N2 * D;
  f32x4 s = *(const f32x4*)(P + i);
  s += *(const f32x4*)(P + S + i);
  s += *(const f32x4*)(P + 2 * S + i);
  s += *(const f32x4*)(P + 3 * S + i);
  *(f32x4*)(Qhat + i) = s;
}

// ---------------------------------------------------------------------------
extern "C" void kernel_launch(void* const* d_in, const int* in_sizes, int n_in,
                              void* d_out, int out_size, void* d_ws, size_t ws_size,
                              hipStream_t stream)
{
  const float* x1 = (const float*)d_in[0];
  const float* x2 = (const float*)d_in[1];
  const float* WQ = (const float*)d_in[2];
  const float* bQ = (const float*)d_in[3];
  const float* WK = (const float*)d_in[4];
  const float* bK = (const float*)d_in[5];
  const float* WV = (const float*)d_in[6];
  const float* bV = (const float*)d_in[7];

  float* out  = (float*)d_out;
  float* Qf   = out;                    // [4,2048,256]
  float* Qhat = out + 2097152;          // [4,2048,256]
  float* attn = out + 4194304;          // [4,2048,4096]

  char* ws = (char*)d_ws;
  bf16* Qb   = (bf16*)(ws + (0ull  << 20));  // 4 MB
  bf16* tQb  = (bf16*)(ws + (4ull  << 20));  // 4 MB
  bf16* Kb   = (bf16*)(ws + (8ull  << 20));  // 8 MB
  bf16* tKb  = (bf16*)(ws + (16ull << 20));  // 8 MB
  bf16* Vt   = (bf16*)(ws + (24ull << 20));  // 8 MB  [b][dk][m]
  bf16* E    = (bf16*)(ws + (32ull << 20));  // 64 MB [b][n][m] bf16 e
  float* partials = (float*)(ws + (96ull << 20));  // 8192*32*4 = 1 MB
  float* partQ    = (float*)(ws + (100ull << 20)); // 32 MB [mh][b][n][dk]

  projQ_kernel    <<<dim3(64, 4),   256, 0, stream>>>(x2, WQ, bQ, Qf, Qb, tQb);
  proj_kernel<1>  <<<dim3(128, 4),  256, 0, stream>>>(x1, WK, bK, Kb, tKb);
  proj_kernel<2>  <<<dim3(2, 256),  256, 0, stream>>>(WV, x1, bV, Vt, nullptr);
  scores_kernel   <<<dim3(32, 16, 4), 512, 0, stream>>>(Qb, tQb, Kb, tKb, E, partials);
  qhat_kernel     <<<dim3(32, 4, 4), 512, 0, stream>>>(E, Vt, partials, attn, partQ);
  reduceQ_kernel  <<<2048, 256, 0, stream>>>(partQ, Qhat);
}

// Round 5
// 178.183 us; speedup vs baseline: 1.2633x; 1.0686x over previous
//
#include <hip/hip_runtime.h>
#include <hip/hip_bf16.h>

typedef __bf16 bf16;
typedef __bf16 bf16x4 __attribute__((ext_vector_type(4)));
typedef __bf16 bf16x8 __attribute__((ext_vector_type(8)));
typedef float  f32x4  __attribute__((ext_vector_type(4)));

#define DEVI static __device__ __forceinline__

constexpr int NB = 4;
constexpr int N1 = 4096;
constexpr int N2 = 2048;
constexpr int D  = 256;   // DIM1 = DIM2 = DK

DEVI f32x4 mfma16(bf16x8 a, bf16x8 b, f32x4 c) {
  return __builtin_amdgcn_mfma_f32_16x16x32_bf16(a, b, c, 0, 0, 0);
}

typedef const __attribute__((address_space(1))) void* gas_t;
typedef __attribute__((address_space(3))) void* las_t;

DEVI void gload_lds16(const void* g, void* l) {
  __builtin_amdgcn_global_load_lds((gas_t)g, (las_t)l, 16, 0, 0);
}

DEVI void fence_sched() { __builtin_amdgcn_sched_barrier(0); }

// ---------------------------------------------------------------------------
// Q projection with hi/lo bf16 split for near-fp32 accuracy on the fp32 Q out.
// ---------------------------------------------------------------------------
__global__ __launch_bounds__(256)
void projQ_kernel(const float* __restrict__ A, const float* __restrict__ Bm,
                  const float* __restrict__ bias,
                  float* __restrict__ outF, bf16* __restrict__ out1,
                  bf16* __restrict__ out2)
{
  __shared__ bf16 Ah[128][64], Al[128][64];
  __shared__ bf16 Bh[64][64],  Bl[64][64];
  const int tid  = threadIdx.x;
  const int lane = tid & 63, wid = tid >> 6;
  const int wr = wid >> 1, wc = wid & 1;
  const int m0 = blockIdx.x * 128, n0 = blockIdx.y * 64;

  f32x4 acc[4][2];
#pragma unroll
  for (int i = 0; i < 4; ++i)
#pragma unroll
    for (int j = 0; j < 2; ++j) acc[i][j] = f32x4{0.f, 0.f, 0.f, 0.f};

  for (int kt = 0; kt < 4; ++kt) {
    const int k0 = kt * 64;
    if (kt) __syncthreads();
#pragma unroll
    for (int i = 0; i < 8; ++i) {
      int idx = i * 256 + tid;
      int r = idx >> 4, c4 = idx & 15;
      const float4 v = *(const float4*)(A + (size_t)(m0 + r) * D + k0 + c4 * 4);
      bf16x4 h, l;
      h[0] = (bf16)v.x; h[1] = (bf16)v.y; h[2] = (bf16)v.z; h[3] = (bf16)v.w;
      l[0] = (bf16)(v.x - (float)h[0]); l[1] = (bf16)(v.y - (float)h[1]);
      l[2] = (bf16)(v.z - (float)h[2]); l[3] = (bf16)(v.w - (float)h[3]);
      *(bf16x4*)&Ah[r][c4 * 4] = h;
      *(bf16x4*)&Al[r][c4 * 4] = l;
    }
#pragma unroll
    for (int i = 0; i < 4; ++i) {
      int idx = i * 256 + tid;
      int r = idx >> 4, c4 = idx & 15;
      const float4 v = *(const float4*)(Bm + (size_t)(n0 + r) * D + k0 + c4 * 4);
      bf16x4 h, l;
      h[0] = (bf16)v.x; h[1] = (bf16)v.y; h[2] = (bf16)v.z; h[3] = (bf16)v.w;
      l[0] = (bf16)(v.x - (float)h[0]); l[1] = (bf16)(v.y - (float)h[1]);
      l[2] = (bf16)(v.z - (float)h[2]); l[3] = (bf16)(v.w - (float)h[3]);
      *(bf16x4*)&Bh[r][c4 * 4] = h;
      *(bf16x4*)&Bl[r][c4 * 4] = l;
    }
    __syncthreads();
#pragma unroll
    for (int kc = 0; kc < 2; ++kc) {
      const int ko = kc * 32 + (lane >> 4) * 8;
      bf16x8 ah[4], al[4];
#pragma unroll
      for (int mf = 0; mf < 4; ++mf) {
        ah[mf] = *(bf16x8*)&Ah[wr * 64 + mf * 16 + (lane & 15)][ko];
        al[mf] = *(bf16x8*)&Al[wr * 64 + mf * 16 + (lane & 15)][ko];
      }
#pragma unroll
      for (int nf = 0; nf < 2; ++nf) {
        bf16x8 bh = *(bf16x8*)&Bh[wc * 32 + nf * 16 + (lane & 15)][ko];
        bf16x8 bl = *(bf16x8*)&Bl[wc * 32 + nf * 16 + (lane & 15)][ko];
#pragma unroll
        for (int mf = 0; mf < 4; ++mf) {
          acc[mf][nf] = mfma16(ah[mf], bh, acc[mf][nf]);
          acc[mf][nf] = mfma16(ah[mf], bl, acc[mf][nf]);
          acc[mf][nf] = mfma16(al[mf], bh, acc[mf][nf]);
        }
      }
    }
  }

#pragma unroll
  for (int nf = 0; nf < 2; ++nf) {
    const int col = n0 + wc * 32 + nf * 16 + (lane & 15);
    const float bcol = bias[col];
#pragma unroll
    for (int mf = 0; mf < 4; ++mf) {
#pragma unroll
      for (int r = 0; r < 4; ++r) {
        const int row = m0 + wr * 64 + mf * 16 + (lane >> 4) * 4 + r;
        float v = acc[mf][nf][r] + bcol;
        outF[(size_t)row * D + col] = v;
        out1[(size_t)row * D + col] = (bf16)v;
        out2[(size_t)row * D + col] = (bf16)tanhf(v);
      }
    }
  }
}

// ---------------------------------------------------------------------------
// K / V^T projections (plain bf16 MFMA).
// ---------------------------------------------------------------------------
template<int MODE>
__global__ __launch_bounds__(256)
void proj_kernel(const float* __restrict__ A, const float* __restrict__ Bm,
                 const float* __restrict__ bias,
                 bf16* __restrict__ out1, bf16* __restrict__ out2)
{
  __shared__ bf16 As[128][64];
  __shared__ bf16 Bs[64][64];
  const int tid  = threadIdx.x;
  const int lane = tid & 63, wid = tid >> 6;
  const int wr = wid >> 1, wc = wid & 1;
  const int m0 = blockIdx.x * 128, n0 = blockIdx.y * 64;

  f32x4 acc[4][2];
#pragma unroll
  for (int i = 0; i < 4; ++i)
#pragma unroll
    for (int j = 0; j < 2; ++j) acc[i][j] = f32x4{0.f, 0.f, 0.f, 0.f};

  for (int kt = 0; kt < 4; ++kt) {
    const int k0 = kt * 64;
    if (kt) __syncthreads();
#pragma unroll
    for (int i = 0; i < 8; ++i) {
      int idx = i * 256 + tid;
      int r = idx >> 4, c4 = idx & 15;
      const float4 v = *(const float4*)(A + (size_t)(m0 + r) * D + k0 + c4 * 4);
      bf16x4 bv; bv[0] = (bf16)v.x; bv[1] = (bf16)v.y; bv[2] = (bf16)v.z; bv[3] = (bf16)v.w;
      *(bf16x4*)&As[r][c4 * 4] = bv;
    }
#pragma unroll
    for (int i = 0; i < 4; ++i) {
      int idx = i * 256 + tid;
      int r = idx >> 4, c4 = idx & 15;
      const float4 v = *(const float4*)(Bm + (size_t)(n0 + r) * D + k0 + c4 * 4);
      bf16x4 bv; bv[0] = (bf16)v.x; bv[1] = (bf16)v.y; bv[2] = (bf16)v.z; bv[3] = (bf16)v.w;
      *(bf16x4*)&Bs[r][c4 * 4] = bv;
    }
    __syncthreads();
#pragma unroll
    for (int kc = 0; kc < 2; ++kc) {
      const int ko = kc * 32 + (lane >> 4) * 8;
      bf16x8 a[4];
#pragma unroll
      for (int mf = 0; mf < 4; ++mf)
        a[mf] = *(bf16x8*)&As[wr * 64 + mf * 16 + (lane & 15)][ko];
#pragma unroll
      for (int nf = 0; nf < 2; ++nf) {
        bf16x8 bb = *(bf16x8*)&Bs[wc * 32 + nf * 16 + (lane & 15)][ko];
#pragma unroll
        for (int mf = 0; mf < 4; ++mf) acc[mf][nf] = mfma16(a[mf], bb, acc[mf][nf]);
      }
    }
  }

#pragma unroll
  for (int nf = 0; nf < 2; ++nf) {
    const int col = n0 + wc * 32 + nf * 16 + (lane & 15);
    float bcol = 0.f;
    if constexpr (MODE == 1) bcol = bias[col];
#pragma unroll
    for (int mf = 0; mf < 4; ++mf) {
#pragma unroll
      for (int r = 0; r < 4; ++r) {
        const int row = m0 + wr * 64 + mf * 16 + (lane >> 4) * 4 + r;
        float v = acc[mf][nf][r];
        if constexpr (MODE == 1) {
          v += bcol;
          out1[(size_t)row * D + col] = (bf16)v;
          out2[(size_t)row * D + col] = (bf16)tanhf(v);
        } else {
          v += bias[row];  // row = dk
          out1[(size_t)(col >> 12) * (D * N1) + (size_t)row * N1 + (col & 4095)] = (bf16)v;
        }
      }
    }
  }
}

// ---------------------------------------------------------------------------
// Scores: e = exp( (Q K^T) * ((tanhQ tanhK^T + 1)*0.5) / 16 ) -> E (bf16);
// partial row sums -> partials[row][mt].
// Tile 128(n) x 128(m), BK=32, 8 waves (2n x 4m), dbuf LDS 64KB (2 blocks/CU),
// counted-vmcnt 2-barrier pipeline. Robust: each iteration's 4 loads are
// fenced between asm memory barriers, so vmcnt(4) retires exactly the prior
// tile's loads regardless of intra-group scheduling.
// ---------------------------------------------------------------------------
__global__ __launch_bounds__(512, 4)
void scores_kernel(const bf16* __restrict__ Qb, const bf16* __restrict__ tQb,
                   const bf16* __restrict__ Kb, const bf16* __restrict__ tKb,
                   bf16* __restrict__ E, float* __restrict__ partials)
{
  __shared__ bf16 SM[2][4][128][32];   // buf, {Qs,tQs,Ks,tKs}
  __shared__ float rowpart[128][4];
  const int tid = threadIdx.x, lane = tid & 63, wid = tid >> 6;
  const int wr = wid >> 2;       // n half (0..1)
  const int wc = wid & 3;        // m quarter (0..3)
  const int lo16 = lane & 15, hi = lane >> 4;
  const int mt = blockIdx.x, nt = blockIdx.y, b = blockIdx.z;
  const int RQ = b * N2 + nt * 128;
  const int RK = b * N1 + mt * 128;

  f32x4 accS[4][2], accP[4][2];
#pragma unroll
  for (int i = 0; i < 4; ++i)
#pragma unroll
    for (int j = 0; j < 2; ++j) {
      accS[i][j] = f32x4{0.f, 0.f, 0.f, 0.f};
      accP[i][j] = f32x4{0.f, 0.f, 0.f, 0.f};
    }

  const int srow = tid >> 2;             // 0..127
  const int scol = (tid & 3) * 8;        // element col within 32

  auto stage = [&](int kt, int buf) {
    const int col = kt * 32 + scol;
    char* base = (char*)&SM[buf][0][0][0] + tid * 16;
    gload_lds16(Qb  + (size_t)(RQ + srow) * D + col, base);
    gload_lds16(tQb + (size_t)(RQ + srow) * D + col, base + 8192);
    gload_lds16(Kb  + (size_t)(RK + srow) * D + col, base + 16384);
    gload_lds16(tKb + (size_t)(RK + srow) * D + col, base + 24576);
  };

  auto cpt = [&](int buf) {
    const int ko = hi * 8;
    bf16x8 aS[4], aT[4];
#pragma unroll
    for (int mf = 0; mf < 4; ++mf) {
      aS[mf] = *(bf16x8*)&SM[buf][0][wr * 64 + mf * 16 + lo16][ko];
      aT[mf] = *(bf16x8*)&SM[buf][1][wr * 64 + mf * 16 + lo16][ko];
    }
#pragma unroll
    for (int nf = 0; nf < 2; ++nf) {
      bf16x8 bS = *(bf16x8*)&SM[buf][2][wc * 32 + nf * 16 + lo16][ko];
      bf16x8 bT = *(bf16x8*)&SM[buf][3][wc * 32 + nf * 16 + lo16][ko];
#pragma unroll
      for (int mf = 0; mf < 4; ++mf) {
        accS[mf][nf] = mfma16(aS[mf], bS, accS[mf][nf]);
        accP[mf][nf] = mfma16(aT[mf], bT, accP[mf][nf]);
      }
    }
  };

  stage(0, 0);
  fence_sched();
  int cur = 0;
#pragma unroll
  for (int kt = 0; kt < 8; ++kt) {
    if (kt < 7) {
      stage(kt + 1, cur ^ 1);
      fence_sched();
      asm volatile("s_waitcnt vmcnt(4)\n\ts_barrier" ::: "memory");
    } else {
      asm volatile("s_waitcnt vmcnt(0)\n\ts_barrier" ::: "memory");
    }
    cpt(cur);
    asm volatile("s_barrier" ::: "memory");
    cur ^= 1;
  }

  // epilogue
#pragma unroll
  for (int mf = 0; mf < 4; ++mf) {
    f32x4 rs = f32x4{0.f, 0.f, 0.f, 0.f};
#pragma unroll
    for (int nf = 0; nf < 2; ++nf) {
      const int m_g = mt * 128 + wc * 32 + nf * 16 + lo16;
#pragma unroll
      for (int r = 0; r < 4; ++r) {
        const int n_g = b * N2 + nt * 128 + wr * 64 + mf * 16 + hi * 4 + r;
        float s = accS[mf][nf][r] * (accP[mf][nf][r] + 1.0f) * 0.03125f;
        float e = __expf(s);
        E[(size_t)n_g * N1 + m_g] = (bf16)e;
        rs[r] += e;
      }
    }
#pragma unroll
    for (int r = 0; r < 4; ++r) {
      float v = rs[r];
      v += __shfl_xor(v, 1); v += __shfl_xor(v, 2);
      v += __shfl_xor(v, 4); v += __shfl_xor(v, 8);
      if (lo16 == 0)
        rowpart[wr * 64 + mf * 16 + hi * 4 + r][wc] = v;
    }
  }
  __syncthreads();
  if (tid < 128) {
    float p = rowpart[tid][0] + rowpart[tid][1] + rowpart[tid][2] + rowpart[tid][3];
    partials[(size_t)(b * N2 + nt * 128 + tid) * 32 + mt] = p;
  }
}

// ---------------------------------------------------------------------------
// Q_hat partial = (E*rinv) @ V over an m-quarter; writes final attn fp32.
// Counted-vmcnt 2-barrier pipeline with sched_barrier(0)-pinned issue regions:
//   [A: procA (ev-wait, 2 stores, ds_write)] | [B: 4 gload_lds] | [C: loadE] | BAR1
// The ev-wait in region A drains ALL prior-iteration VMEM (loadE was the
// newest op of the previous iteration under the fences), so the staged B tile
// is provably complete before cptq. BAR1 counts are exact: 7 / 6 / 0.
// ---------------------------------------------------------------------------
__global__ __launch_bounds__(512, 4)
void qhat_kernel(const bf16* __restrict__ E, const bf16* __restrict__ Vt,
                 const float* __restrict__ partials,
                 float* __restrict__ attn, bf16* __restrict__ partQ)
{
  __shared__ bf16 As[2][64][64];
  __shared__ bf16 Bs[2][256][64];
  const int tid = threadIdx.x, lane = tid & 63, wid = tid >> 6;
  const int lo16 = lane & 15, hi = lane >> 4, sw = lane & 7;
  const int n0 = blockIdx.x * 64;
  const int mh = blockIdx.y;
  const int b  = blockIdx.z;
  const int mq = mh * 1024;
  const int arow = tid >> 3;          // 0..63
  const int mo   = (tid & 7) * 8;     // 0..56
  const size_t rglob = (size_t)b * N2 + n0 + arow;

  // rinv: each thread sums its row's 32 partials
  float s = 0.f;
  {
    const float* pr = partials + rglob * 32;
#pragma unroll
    for (int j = 0; j < 32; ++j) s += pr[j];
  }
  const float inv = 1.0f / s;

  const bf16* erow  = E    + rglob * N1 + mq;
  float*      aorow = attn + rglob * N1 + mq;
  const bf16* vbase = Vt + (size_t)b * (D * N1) + mq;
  const int awcol = ((tid & 7) ^ (arow & 7)) << 3;  // swizzled A write col

  f32x4 acc[4][2];
#pragma unroll
  for (int i = 0; i < 4; ++i)
#pragma unroll
    for (int j = 0; j < 2; ++j) acc[i][j] = f32x4{0.f, 0.f, 0.f, 0.f};

  auto loadE = [&](int ms) -> bf16x8 {
    return *(const bf16x8*)(erow + ms * 64 + mo);
  };
  auto stageB = [&](int ms, int buf) {
#pragma unroll
    for (int i = 0; i < 4; ++i) {
      const int c = i * 512 + tid;
      const int row = c >> 3;  // dk 0..255
      gload_lds16(vbase + (size_t)row * N1 + ms * 64 + (((c & 7) ^ (row & 7)) << 3),
                  (char*)&Bs[buf][0][0] + c * 16);
    }
  };
  auto procA = [&](int ms, int buf, bf16x8 e) {
    float v[8]; bf16x8 svv;
#pragma unroll
    for (int j = 0; j < 8; ++j) { v[j] = (float)e[j] * inv; svv[j] = (bf16)v[j]; }
    float4 w0 = {v[0], v[1], v[2], v[3]};
    float4 w1 = {v[4], v[5], v[6], v[7]};
    *(float4*)(aorow + ms * 64 + mo)     = w0;
    *(float4*)(aorow + ms * 64 + mo + 4) = w1;
    *(bf16x8*)((char*)&As[buf][arow][0] + awcol * 2) = svv;
  };
  auto cptq = [&](int buf) {
#pragma unroll
    for (int kc = 0; kc < 2; ++kc) {
      const int ko = (((kc * 4 + hi) ^ sw) << 3);
      bf16x8 a[4];
#pragma unroll
      for (int mf = 0; mf < 4; ++mf)
        a[mf] = *(bf16x8*)&As[buf][mf * 16 + lo16][ko];
#pragma unroll
      for (int nf = 0; nf < 2; ++nf) {
        bf16x8 bb = *(bf16x8*)&Bs[buf][wid * 32 + nf * 16 + lo16][ko];
#pragma unroll
        for (int mf = 0; mf < 4; ++mf) acc[mf][nf] = mfma16(a[mf], bb, acc[mf][nf]);
      }
    }
  };

  bf16x8 ev[2];
  ev[0] = loadE(0);
  procA(0, 0, ev[0]);       // ev-wait; 2 stores + ds_write
  fence_sched();
  stageB(0, 0);             // 4 loads
  fence_sched();
  ev[1] = loadE(1);         // 1 load (newest before loop)
  fence_sched();

  int cur = 0;
#pragma unroll
  for (int ms = 0; ms < 16; ++ms) {
    if (ms < 15) {
      procA(ms + 1, cur ^ 1, ev[(ms + 1) & 1]);  // ev-wait drains all older VMEM
      fence_sched();
      stageB(ms + 1, cur ^ 1);
      fence_sched();
      if (ms < 14) { ev[ms & 1] = loadE(ms + 2); fence_sched(); }
    }
    // BAR1: exact outstanding counts under the fences (7 / 6 / 0);
    // lgkmcnt(0) drains own ds_write before the barrier.
    if (ms < 14)
      asm volatile("s_waitcnt vmcnt(7) lgkmcnt(0)\n\ts_barrier" ::: "memory");
    else if (ms == 14)
      asm volatile("s_waitcnt vmcnt(6) lgkmcnt(0)\n\ts_barrier" ::: "memory");
    else
      asm volatile("s_waitcnt vmcnt(0) lgkmcnt(0)\n\ts_barrier" ::: "memory");
    cptq(cur);
    asm volatile("s_barrier" ::: "memory");  // BAR2: reads done before restage
    cur ^= 1;
  }

#pragma unroll
  for (int mf = 0; mf < 4; ++mf)
#pragma unroll
    for (int nf = 0; nf < 2; ++nf)
#pragma unroll
      for (int r = 0; r < 4; ++r) {
        const int n  = n0 + mf * 16 + hi * 4 + r;
        const int dk = wid * 32 + nf * 16 + lo16;
        partQ[((size_t)(mh * NB + b) * N2 + n) * D + dk] = (bf16)acc[mf][nf][r];
      }
}

// ---------------------------------------------------------------------------
__global__ __launch_bounds__(256)
void reduceQ_kernel(const bf16* __restrict__ P, float* __restrict__ Qhat)
{
  const size_t i = ((size_t)blockIdx.x * 256 + threadIdx.x) * 8;
  const size_t S = (size_t)NB * N2 * D;
  bf16x8 p0 = *(const bf16x8*)(P + i);
  bf16x8 p1 = *(const bf16x8*)(P + S + i);
  bf16x8 p2 = *(const bf16x8*)(P + 2 * S + i);
  bf16x8 p3 = *(const bf16x8*)(P + 3 * S + i);
  float o[8];
#pragma unroll
  for (int j = 0; j < 8; ++j)
    o[j] = ((float)p0[j] + (float)p1[j]) + ((float)p2[j] + (float)p3[j]);
  float4 w0 = {o[0], o[1], o[2], o[3]};
  float4 w1 = {o[4], o[5], o[6], o[7]};
  *(float4*)(Qhat + i)     = w0;
  *(float4*)(Qhat + i + 4) = w1;
}

// ---------------------------------------------------------------------------
extern "C" void kernel_launch(void* const* d_in, const int* in_sizes, int n_in,
                              void* d_out, int out_size, void* d_ws, size_t ws_size,
                              hipStream_t stream)
{
  const float* x1 = (const float*)d_in[0];
  const float* x2 = (const float*)d_in[1];
  const float* WQ = (const float*)d_in[2];
  const float* bQ = (const float*)d_in[3];
  const float* WK = (const float*)d_in[4];
  const float* bK = (const float*)d_in[5];
  const float* WV = (const float*)d_in[6];
  const float* bV = (const float*)d_in[7];

  float* out  = (float*)d_out;
  float* Qf   = out;                    // [4,2048,256]
  float* Qhat = out + 2097152;          // [4,2048,256]
  float* attn = out + 4194304;          // [4,2048,4096]

  char* ws = (char*)d_ws;
  bf16* Qb   = (bf16*)(ws + (0ull  << 20));  // 4 MB
  bf16* tQb  = (bf16*)(ws + (4ull  << 20));  // 4 MB
  bf16* Kb   = (bf16*)(ws + (8ull  << 20));  // 8 MB
  bf16* tKb  = (bf16*)(ws + (16ull << 20));  // 8 MB
  bf16* Vt   = (bf16*)(ws + (24ull << 20));  // 8 MB  [b][dk][m]
  bf16* E    = (bf16*)(ws + (32ull << 20));  // 64 MB [b][n][m] bf16 e
  float* partials = (float*)(ws + (96ull << 20));  // 1 MB
  bf16*  partQ    = (bf16*)(ws + (100ull << 20));  // 16 MB [mh][b][n][dk]

  projQ_kernel    <<<dim3(64, 4),   256, 0, stream>>>(x2, WQ, bQ, Qf, Qb, tQb);
  proj_kernel<1>  <<<dim3(128, 4),  256, 0, stream>>>(x1, WK, bK, Kb, tKb);
  proj_kernel<2>  <<<dim3(2, 256),  256, 0, stream>>>(WV, x1, bV, Vt, nullptr);
  scores_kernel   <<<dim3(32, 16, 4), 512, 0, stream>>>(Qb, tQb, Kb, tKb, E, partials);
  qhat_kernel     <<<dim3(32, 4, 4), 512, 0, stream>>>(E, Vt, partials, attn, partQ);
  reduceQ_kernel  <<<1024, 256, 0, stream>>>(partQ, Qhat);
}